// Round 1
// 793.792 us; speedup vs baseline: 1.1114x; 1.1114x over previous
//
#include <hip/hip_runtime.h>
#include <cstdint>
#include <cstddef>

#define N_TOK 16384
#define E_DIM 512
#define C_DIM 8
#define K_CODES 8192
#define LN_EPS 1e-5f

typedef __attribute__((ext_vector_type(8))) short short8;
typedef __attribute__((ext_vector_type(4))) float f32x4;

// ---------- helpers: fp32 -> bf16 round-nearest-even, hi/lo split ----------
__device__ __forceinline__ unsigned short bf16_rn(float x) {
  unsigned u = __float_as_uint(x);
  unsigned r = u + 0x7FFFu + ((u >> 16) & 1u);
  return (unsigned short)(r >> 16);
}
__device__ __forceinline__ float bf16_f(unsigned short h) {
  return __uint_as_float(((unsigned)h) << 16);
}

__device__ __forceinline__ void gload16(const void* g, void* l) {
  __builtin_amdgcn_global_load_lds(
      (const __attribute__((address_space(1))) void*)g,
      (__attribute__((address_space(3))) void*)l, 16, 0, 0);
}

// ---------- pack A (M x 512 fp32 row-major) -> hi/lo bf16, fragment-linear ----------
// packed index t = (mf*16 + kt)*64 + lane ; entry = A[mf*16 + (l&15)][kt*32 + (l>>4)*8 + j]
__global__ __launch_bounds__(256) void pack_a(const float* __restrict__ A,
    unsigned short* __restrict__ hi, unsigned short* __restrict__ lo) {
  int t = blockIdx.x * 256 + threadIdx.x;
  int l = t & 63;
  int kt = (t >> 6) & 15;
  int mf = t >> 10;
  const float* src = A + (size_t)(mf * 16 + (l & 15)) * 512 + kt * 32 + (l >> 4) * 8;
  float4 x0 = *(const float4*)src;
  float4 x1 = *(const float4*)(src + 4);
  float xs[8] = {x0.x, x0.y, x0.z, x0.w, x1.x, x1.y, x1.z, x1.w};
  unsigned hw[4], lw[4];
#pragma unroll
  for (int p = 0; p < 4; ++p) {
    float a = xs[2 * p], b = xs[2 * p + 1];
    unsigned short ha = bf16_rn(a), hb = bf16_rn(b);
    unsigned short la = bf16_rn(a - bf16_f(ha)), lb = bf16_rn(b - bf16_f(hb));
    hw[p] = (unsigned)ha | ((unsigned)hb << 16);
    lw[p] = (unsigned)la | ((unsigned)lb << 16);
  }
  uint4 hv; hv.x = hw[0]; hv.y = hw[1]; hv.z = hw[2]; hv.w = hw[3];
  uint4 lv; lv.x = lw[0]; lv.y = lw[1]; lv.z = lw[2]; lv.w = lw[3];
  ((uint4*)hi)[t] = hv;
  ((uint4*)lo)[t] = lv;
}

// ---------- pack B (512 x 512 fp32 row-major, K x N) -> hi/lo bf16, fragment-linear ----------
// packed index t = (nf*16 + kt)*64 + lane ; entry = B[kt*32 + (l>>4)*8 + j][nf*16 + (l&15)]
__global__ __launch_bounds__(256) void pack_b(const float* __restrict__ B,
    unsigned short* __restrict__ hi, unsigned short* __restrict__ lo) {
  int t = blockIdx.x * 256 + threadIdx.x;   // 32*16*64 = 32768 total
  int l = t & 63;
  int kt = (t >> 6) & 15;
  int nf = t >> 10;
  int col = nf * 16 + (l & 15);
  int krow = kt * 32 + (l >> 4) * 8;
  unsigned hw[4], lw[4];
#pragma unroll
  for (int p = 0; p < 4; ++p) {
    float a = B[(size_t)(krow + 2 * p) * 512 + col];
    float b = B[(size_t)(krow + 2 * p + 1) * 512 + col];
    unsigned short ha = bf16_rn(a), hb = bf16_rn(b);
    unsigned short la = bf16_rn(a - bf16_f(ha)), lb = bf16_rn(b - bf16_f(hb));
    hw[p] = (unsigned)ha | ((unsigned)hb << 16);
    lw[p] = (unsigned)la | ((unsigned)lb << 16);
  }
  uint4 hv; hv.x = hw[0]; hv.y = hw[1]; hv.z = hw[2]; hv.w = hw[3];
  uint4 lv; lv.x = lw[0]; lv.y = lw[1]; lv.z = lw[2]; lv.w = lw[3];
  ((uint4*)hi)[t] = hv;
  ((uint4*)lo)[t] = lv;
}

// ---------- split-bf16 MFMA GEMM: C = op(A@B + bias), N=K=512 hardcoded ----------
// BM=128 BN=128 BK=32, 4 waves (2x2), wave tile 64x64 = 4x4 fragments of 16x16
// acc += Ahi*Bhi + Ahi*Blo + Alo*Bhi   (fp32-accurate to ~2^-16 relative)
template<bool RELU>
__global__ __launch_bounds__(256) void gemm_mfma(const unsigned short* __restrict__ Ah,
    const unsigned short* __restrict__ Al, const unsigned short* __restrict__ Bh,
    const unsigned short* __restrict__ Bl, const float* __restrict__ bias,
    float* __restrict__ C) {
  __shared__ char smem[32768];   // Ahi 8K | Alo 8K | Bhi 8K | Blo 8K (frag-linear)
  const int tid = threadIdx.x;
  const int l = tid & 63;
  const int w = tid >> 6;
  const int wm = w >> 1, wn = w & 1;
  const int mblk = blockIdx.y, nblk = blockIdx.x;

  char* sAh = smem;
  char* sAl = smem + 8192;
  char* sBh = smem + 16384;
  char* sBl = smem + 24576;

  // per-lane global byte addrs of (frag = 2w, kt = 0); next frag is +16*1024 bytes
  const char* gAh = (const char*)Ah + (((size_t)(mblk * 8 + 2 * w) * 16) * 64 + l) * 16;
  const char* gAl = (const char*)Al + (((size_t)(mblk * 8 + 2 * w) * 16) * 64 + l) * 16;
  const char* gBh = (const char*)Bh + (((size_t)(nblk * 8 + 2 * w) * 16) * 64 + l) * 16;
  const char* gBl = (const char*)Bl + (((size_t)(nblk * 8 + 2 * w) * 16) * 64 + l) * 16;
  char* dA0 = sAh + (2 * w) * 1024;  // wave-uniform LDS dests
  char* dA1 = sAl + (2 * w) * 1024;
  char* dB0 = sBh + (2 * w) * 1024;
  char* dB1 = sBl + (2 * w) * 1024;

  f32x4 acc[4][4];
#pragma unroll
  for (int i = 0; i < 4; ++i)
#pragma unroll
    for (int j = 0; j < 4; ++j) acc[i][j] = (f32x4){0.f, 0.f, 0.f, 0.f};

  for (int kt = 0; kt < 16; ++kt) {
    __syncthreads();               // previous iteration's LDS reads complete
    const size_t ko = (size_t)kt * 1024;
    gload16(gAh + ko,           dA0);
    gload16(gAh + ko + 16384,   dA0 + 1024);
    gload16(gAl + ko,           dA1);
    gload16(gAl + ko + 16384,   dA1 + 1024);
    gload16(gBh + ko,           dB0);
    gload16(gBh + ko + 16384,   dB0 + 1024);
    gload16(gBl + ko,           dB1);
    gload16(gBl + ko + 16384,   dB1 + 1024);
    __syncthreads();               // vmcnt(0) drained before barrier -> tiles ready

    short8 a_h[4], a_l[4], b_h[4], b_l[4];
#pragma unroll
    for (int i = 0; i < 4; ++i) {
      a_h[i] = ((const short8*)sAh)[(wm * 4 + i) * 64 + l];
      a_l[i] = ((const short8*)sAl)[(wm * 4 + i) * 64 + l];
    }
#pragma unroll
    for (int j = 0; j < 4; ++j) {
      b_h[j] = ((const short8*)sBh)[(wn * 4 + j) * 64 + l];
      b_l[j] = ((const short8*)sBl)[(wn * 4 + j) * 64 + l];
    }
#pragma unroll
    for (int i = 0; i < 4; ++i)
#pragma unroll
      for (int j = 0; j < 4; ++j) {
        acc[i][j] = __builtin_amdgcn_mfma_f32_16x16x32_bf16(a_h[i], b_h[j], acc[i][j], 0, 0, 0);
        acc[i][j] = __builtin_amdgcn_mfma_f32_16x16x32_bf16(a_h[i], b_l[j], acc[i][j], 0, 0, 0);
        acc[i][j] = __builtin_amdgcn_mfma_f32_16x16x32_bf16(a_l[i], b_h[j], acc[i][j], 0, 0, 0);
      }
  }

  // epilogue: D col = lane&15, row = (lane>>4)*4 + r  (m89/m91-verified layout)
  const int colb = nblk * 128 + wn * 64 + (l & 15);
  const int rowb = mblk * 128 + wm * 64 + ((l >> 4) << 2);
#pragma unroll
  for (int j = 0; j < 4; ++j) {
    float bv = bias[colb + j * 16];
#pragma unroll
    for (int i = 0; i < 4; ++i) {
#pragma unroll
      for (int r = 0; r < 4; ++r) {
        float v = acc[i][j][r] + bv;
        if (RELU) v = fmaxf(v, 0.f);
        C[(size_t)(rowb + i * 16 + r) * 512 + colb + j * 16] = v;
      }
    }
  }
}

// ---------- z = LN(h @ W2_in + b2) over C=8; one wave per token ----------
__global__ __launch_bounds__(256) void zln_kernel(const float* __restrict__ h,
    const float* __restrict__ W2, const float* __restrict__ b2,
    const float* __restrict__ g, const float* __restrict__ b,
    float* __restrict__ z) {
  int token = blockIdx.x * 4 + (threadIdx.x >> 6);
  int lane = threadIdx.x & 63;
  const float* hr = h + (size_t)token * E_DIM;
  float acc[C_DIM];
#pragma unroll
  for (int c = 0; c < C_DIM; ++c) acc[c] = 0.f;
  for (int e = lane; e < E_DIM; e += 64) {
    float hv = hr[e];
    const float* w = W2 + e * C_DIM;
#pragma unroll
    for (int c = 0; c < C_DIM; ++c) acc[c] = fmaf(hv, w[c], acc[c]);
  }
#pragma unroll
  for (int c = 0; c < C_DIM; ++c) {
#pragma unroll
    for (int off = 32; off > 0; off >>= 1) acc[c] += __shfl_down(acc[c], off);
  }
  if (lane == 0) {
    float v[C_DIM]; float mu = 0.f;
#pragma unroll
    for (int c = 0; c < C_DIM; ++c) { v[c] = acc[c] + b2[c]; mu += v[c]; }
    mu *= 0.125f;
    float var = 0.f;
#pragma unroll
    for (int c = 0; c < C_DIM; ++c) { float d = v[c] - mu; var += d * d; }
    var *= 0.125f;
    float inv = 1.0f / sqrtf(var + LN_EPS);
#pragma unroll
    for (int c = 0; c < C_DIM; ++c)
      z[(size_t)token * C_DIM + c] = ((v[c] - mu) * inv) * g[c] + b[c];
  }
}

// ---------- ||e||^2 per code ----------
__global__ void ne_kernel(const float* __restrict__ emb, float* __restrict__ ne) {
  int k = blockIdx.x * 256 + threadIdx.x;
  const float* e = emb + (size_t)k * C_DIM;
  float s = 0.f;
#pragma unroll
  for (int c = 0; c < C_DIM; ++c) s = fmaf(e[c], e[c], s);
  ne[k] = s;
}

// ---------- partial argmin: lane=token, code index uniform (scalar loads) ----------
__global__ __launch_bounds__(256) void vq_partial(const float* __restrict__ z,
    const float* __restrict__ emb, const float* __restrict__ ne,
    float* __restrict__ pbest, int* __restrict__ pidx) {
  int chunk = blockIdx.x & 7;                 // 8 chunks of 1024 codes
  int token = (blockIdx.x >> 3) * 256 + threadIdx.x;
  float zv[C_DIM];
#pragma unroll
  for (int c = 0; c < C_DIM; ++c) zv[c] = z[(size_t)token * C_DIM + c];
  float s = 0.f;
#pragma unroll
  for (int c = 0; c < C_DIM; ++c) s = fmaf(zv[c], zv[c], s);
  float best = 3.402823466e38f; int bi = 0;
  int j0 = chunk * 1024;
  for (int j = j0; j < j0 + 1024; ++j) {
    const float* e = emb + (size_t)j * C_DIM;  // uniform address -> s_load
    float p = 0.f;
#pragma unroll
    for (int c = 0; c < C_DIM; ++c) p = fmaf(zv[c], e[c], p);
    float d = fmaf(-2.f, p, s) + ne[j];
    if (d < best) { best = d; bi = j; }        // strict < : first-occurrence argmin
  }
  pbest[chunk * N_TOK + token] = best;
  pidx[chunk * N_TOK + token] = bi;
}

// ---------- combine 8 chunk-partials (ascending chunk keeps first-occurrence) ----------
__global__ void vq_combine(const float* __restrict__ pbest, const int* __restrict__ pidx,
    int* __restrict__ idx_i, float* __restrict__ idxf) {
  int n = blockIdx.x * 256 + threadIdx.x;
  float best = pbest[n]; int bi = pidx[n];
#pragma unroll
  for (int c = 1; c < 8; ++c) {
    float bb = pbest[c * N_TOK + n]; int i2 = pidx[c * N_TOK + n];
    if (bb < best) { best = bb; bi = i2; }
  }
  idx_i[n] = bi;
  idxf[n] = (float)bi;
}

// ---------- t = relu(emb @ W1_out + b1_out)  (K,8)@(8,E) ----------
__global__ __launch_bounds__(128) void proj_out1(const float* __restrict__ emb,
    const float* __restrict__ W1, const float* __restrict__ b1, float* __restrict__ t) {
  int k = blockIdx.x;
  int e = threadIdx.x * 4;
  float4 acc = *(const float4*)(b1 + e);
#pragma unroll
  for (int c = 0; c < C_DIM; ++c) {
    float ev = emb[(size_t)k * C_DIM + c];
    float4 w = *(const float4*)(W1 + (size_t)c * E_DIM + e);
    acc.x = fmaf(ev, w.x, acc.x); acc.y = fmaf(ev, w.y, acc.y);
    acc.z = fmaf(ev, w.z, acc.z); acc.w = fmaf(ev, w.w, acc.w);
  }
  acc.x = fmaxf(acc.x, 0.f); acc.y = fmaxf(acc.y, 0.f);
  acc.z = fmaxf(acc.z, 0.f); acc.w = fmaxf(acc.w, 0.f);
  *(float4*)(t + (size_t)k * E_DIM + e) = acc;
}

// ---------- in-place LayerNorm over rows of 512 ----------
__global__ __launch_bounds__(256) void ln512(float* __restrict__ g,
    const float* __restrict__ gw, const float* __restrict__ bw) {
  int row = blockIdx.x; int tid = threadIdx.x;
  float* r = g + (size_t)row * E_DIM;
  float v0 = r[tid], v1 = r[tid + 256];
  __shared__ float red[8];
  int lane = tid & 63, wid = tid >> 6;
  float sum = v0 + v1;
#pragma unroll
  for (int off = 32; off > 0; off >>= 1) sum += __shfl_xor(sum, off);
  if (lane == 0) red[wid] = sum;
  __syncthreads();
  float mu = (red[0] + red[1] + red[2] + red[3]) * (1.0f / 512.0f);
  float d0 = v0 - mu, d1 = v1 - mu;
  float sq = d0 * d0 + d1 * d1;
#pragma unroll
  for (int off = 32; off > 0; off >>= 1) sq += __shfl_xor(sq, off);
  if (lane == 0) red[4 + wid] = sq;
  __syncthreads();
  float var = (red[4] + red[5] + red[6] + red[7]) * (1.0f / 512.0f);
  float inv = 1.0f / sqrtf(var + LN_EPS);
  r[tid]       = (d0 * inv) * gw[tid] + bw[tid];
  r[tid + 256] = (d1 * inv) * gw[tid + 256] + bw[tid + 256];
}

// ---------- q[n] = oc[idx[n]] ----------
__global__ __launch_bounds__(128) void out_gather(const float* __restrict__ oc,
    const int* __restrict__ idx_i, float* __restrict__ q) {
  int n = blockIdx.x;
  int k = idx_i[n];
  int e = threadIdx.x * 4;
  *(float4*)(q + (size_t)n * E_DIM + e) = *(const float4*)(oc + (size_t)k * E_DIM + e);
}

// ---------- scatter ones into zeroed encodings ----------
__global__ void scatter_ones(const float* __restrict__ idxf, float* __restrict__ enc) {
  int n = blockIdx.x * 256 + threadIdx.x;
  int k = (int)idxf[n];
  enc[(size_t)n * K_CODES + k] = 1.0f;
}

extern "C" void kernel_launch(void* const* d_in, const int* in_sizes, int n_in,
                              void* d_out, int out_size, void* d_ws, size_t ws_size,
                              hipStream_t stream) {
  const float* features = (const float*)d_in[0];
  const float* W1_in  = (const float*)d_in[1];
  const float* b1_in  = (const float*)d_in[2];
  const float* W2_in  = (const float*)d_in[3];
  const float* b2_in  = (const float*)d_in[4];
  const float* ln_in_g = (const float*)d_in[5];
  const float* ln_in_b = (const float*)d_in[6];
  const float* emb    = (const float*)d_in[7];
  const float* W1_out = (const float*)d_in[8];
  const float* b1_out = (const float*)d_in[9];
  const float* W2_out = (const float*)d_in[10];
  const float* b2_out = (const float*)d_in[11];
  const float* ln_out_g = (const float*)d_in[12];
  const float* ln_out_b = (const float*)d_in[13];

  float* q    = (float*)d_out;                       // N*E
  float* idxf = q + (size_t)N_TOK * E_DIM;           // N (as float)
  float* enc  = idxf + N_TOK;                        // N*K one-hot

  // Use the 537 MB encodings region as scratch; memset+scatter happen last.
  float* h     = enc;                        // 16384*512
  float* t     = enc + 8388608;              // 8192*512
  float* g     = enc + 12582912;             // 8192*512
  float* z     = enc + 16777216;             // 16384*8
  float* ne    = enc + 16908288;             // 8192
  float* pbest = enc + 16916480;             // 8*16384
  int*   idx_i = (int*)(enc + 17047552);     // 16384
  int*   pidx  = (int*)(enc + 17063936);     // 8*16384
  unsigned short* A1h = (unsigned short*)(enc + 17195008);  // 16384*512 bf16
  unsigned short* A1l = (unsigned short*)(enc + 21389312);
  unsigned short* A2h = (unsigned short*)(enc + 25583616);  // 8192*512 bf16
  unsigned short* A2l = (unsigned short*)(enc + 27680768);
  unsigned short* B1h = (unsigned short*)(enc + 29777920);  // 512*512 bf16
  unsigned short* B1l = (unsigned short*)(enc + 29908992);
  unsigned short* B2h = (unsigned short*)(enc + 30040064);
  unsigned short* B2l = (unsigned short*)(enc + 30171136);

  ne_kernel<<<K_CODES / 256, 256, 0, stream>>>(emb, ne);

  // ---- project_in: h = relu(features @ W1_in + b1) via split-bf16 MFMA ----
  pack_b<<<128, 256, 0, stream>>>(W1_in, B1h, B1l);
  pack_a<<<4096, 256, 0, stream>>>(features, A1h, A1l);
  dim3 g1(4, N_TOK / 128);
  gemm_mfma<true><<<g1, 256, 0, stream>>>(A1h, A1l, B1h, B1l, b1_in, h);

  zln_kernel<<<N_TOK / 4, 256, 0, stream>>>(h, W2_in, b2_in, ln_in_g, ln_in_b, z);

  vq_partial<<<(N_TOK / 256) * 8, 256, 0, stream>>>(z, emb, ne, pbest, pidx);
  vq_combine<<<N_TOK / 256, 256, 0, stream>>>(pbest, pidx, idx_i, idxf);

  // ---- project_out over codebook: g = (relu(emb@W1_out+b1)) @ W2_out + b2 ----
  proj_out1<<<K_CODES, 128, 0, stream>>>(emb, W1_out, b1_out, t);
  pack_b<<<128, 256, 0, stream>>>(W2_out, B2h, B2l);
  pack_a<<<2048, 256, 0, stream>>>(t, A2h, A2l);
  dim3 g2(4, K_CODES / 128);
  gemm_mfma<false><<<g2, 256, 0, stream>>>(A2h, A2l, B2h, B2l, b2_out, g);

  ln512<<<K_CODES, 256, 0, stream>>>(g, ln_out_g, ln_out_b);

  out_gather<<<N_TOK, 128, 0, stream>>>(g, idx_i, q);

  hipMemsetAsync(enc, 0, (size_t)N_TOK * K_CODES * sizeof(float), stream);
  scatter_ones<<<N_TOK / 256, 256, 0, stream>>>(idxf, enc);
}

// Round 2
// 788.326 us; speedup vs baseline: 1.1191x; 1.0069x over previous
//
#include <hip/hip_runtime.h>
#include <cstdint>
#include <cstddef>

#define N_TOK 16384
#define E_DIM 512
#define C_DIM 8
#define K_CODES 8192
#define LN_EPS 1e-5f

typedef __attribute__((ext_vector_type(8))) short short8;
typedef __attribute__((ext_vector_type(4))) float f32x4;

// ---------- helpers: fp32 -> bf16 round-nearest-even, hi/lo split ----------
__device__ __forceinline__ unsigned short bf16_rn(float x) {
  unsigned u = __float_as_uint(x);
  unsigned r = u + 0x7FFFu + ((u >> 16) & 1u);
  return (unsigned short)(r >> 16);
}
__device__ __forceinline__ float bf16_f(unsigned short h) {
  return __uint_as_float(((unsigned)h) << 16);
}

__device__ __forceinline__ void gload16(const void* g, void* l) {
  __builtin_amdgcn_global_load_lds(
      (const __attribute__((address_space(1))) void*)g,
      (__attribute__((address_space(3))) void*)l, 16, 0, 0);
}

// ---------- pack bodies (fragment-linear hi/lo bf16) ----------
// A (M x 512 row-major): t = (mf*16 + kt)*64 + l ; entry = A[mf*16+(l&15)][kt*32+(l>>4)*8 + j]
__device__ __forceinline__ void pack_a_body(const float* __restrict__ A,
    unsigned short* __restrict__ hi, unsigned short* __restrict__ lo, int t) {
  int l = t & 63;
  int kt = (t >> 6) & 15;
  int mf = t >> 10;
  const float* src = A + (size_t)(mf * 16 + (l & 15)) * 512 + kt * 32 + (l >> 4) * 8;
  float4 x0 = *(const float4*)src;
  float4 x1 = *(const float4*)(src + 4);
  float xs[8] = {x0.x, x0.y, x0.z, x0.w, x1.x, x1.y, x1.z, x1.w};
  unsigned hw[4], lw[4];
#pragma unroll
  for (int p = 0; p < 4; ++p) {
    float a = xs[2 * p], b = xs[2 * p + 1];
    unsigned short ha = bf16_rn(a), hb = bf16_rn(b);
    unsigned short la = bf16_rn(a - bf16_f(ha)), lb = bf16_rn(b - bf16_f(hb));
    hw[p] = (unsigned)ha | ((unsigned)hb << 16);
    lw[p] = (unsigned)la | ((unsigned)lb << 16);
  }
  uint4 hv; hv.x = hw[0]; hv.y = hw[1]; hv.z = hw[2]; hv.w = hw[3];
  uint4 lv; lv.x = lw[0]; lv.y = lw[1]; lv.z = lw[2]; lv.w = lw[3];
  ((uint4*)hi)[t] = hv;
  ((uint4*)lo)[t] = lv;
}

// B (512 x 512 K x N row-major): t = (nf*16 + kt)*64 + l ; entry = B[kt*32+(l>>4)*8+j][nf*16+(l&15)]
__device__ __forceinline__ void pack_b_body(const float* __restrict__ B,
    unsigned short* __restrict__ hi, unsigned short* __restrict__ lo, int t) {
  int l = t & 63;
  int kt = (t >> 6) & 15;
  int nf = t >> 10;
  int col = nf * 16 + (l & 15);
  int krow = kt * 32 + (l >> 4) * 8;
  unsigned hw[4], lw[4];
#pragma unroll
  for (int p = 0; p < 4; ++p) {
    float a = B[(size_t)(krow + 2 * p) * 512 + col];
    float b = B[(size_t)(krow + 2 * p + 1) * 512 + col];
    unsigned short ha = bf16_rn(a), hb = bf16_rn(b);
    unsigned short la = bf16_rn(a - bf16_f(ha)), lb = bf16_rn(b - bf16_f(hb));
    hw[p] = (unsigned)ha | ((unsigned)hb << 16);
    lw[p] = (unsigned)la | ((unsigned)lb << 16);
  }
  uint4 hv; hv.x = hw[0]; hv.y = hw[1]; hv.z = hw[2]; hv.w = hw[3];
  uint4 lv; lv.x = lw[0]; lv.y = lw[1]; lv.z = lw[2]; lv.w = lw[3];
  ((uint4*)hi)[t] = hv;
  ((uint4*)lo)[t] = lv;
}

// ---------- fused prep: pack_a(features) | pack_b(W1_in) | pack_b(W2_out) | ne ----------
__global__ __launch_bounds__(256) void prep(const float* __restrict__ features,
    const float* __restrict__ W1_in, const float* __restrict__ W2_out,
    const float* __restrict__ emb,
    unsigned short* __restrict__ A1h, unsigned short* __restrict__ A1l,
    unsigned short* __restrict__ B1h, unsigned short* __restrict__ B1l,
    unsigned short* __restrict__ B2h, unsigned short* __restrict__ B2l,
    float* __restrict__ ne) {
  int bid = blockIdx.x;
  int tid = threadIdx.x;
  if (bid < 4096) {
    pack_a_body(features, A1h, A1l, bid * 256 + tid);
  } else if (bid < 4224) {
    pack_b_body(W1_in, B1h, B1l, (bid - 4096) * 256 + tid);
  } else if (bid < 4352) {
    pack_b_body(W2_out, B2h, B2l, (bid - 4224) * 256 + tid);
  } else {
    int k = (bid - 4352) * 256 + tid;
    const float* e = emb + (size_t)k * C_DIM;
    float s = 0.f;
#pragma unroll
    for (int c = 0; c < C_DIM; ++c) s = fmaf(e[c], e[c], s);
    ne[k] = s;
  }
}

// ---------- split-bf16 MFMA GEMM, 2-phase pipelined (T3-min), N=K=512 ----------
// BM=128 BN=128 BK=32, 4 waves (2x2), wave tile 64x64 = 4x4 fragments of 16x16
// acc += Ahi*Bhi + Ahi*Blo + Alo*Bhi   (fp32-accurate to ~2^-16 relative)
template<bool RELU>
__global__ __launch_bounds__(256) void gemm_mfma(const unsigned short* __restrict__ Ah,
    const unsigned short* __restrict__ Al, const unsigned short* __restrict__ Bh,
    const unsigned short* __restrict__ Bl, const float* __restrict__ bias,
    float* __restrict__ C) {
  __shared__ char smem[65536];   // 2 buffers x (Ahi 8K | Alo 8K | Bhi 8K | Blo 8K)
  const int tid = threadIdx.x;
  const int l = tid & 63;
  const int w = tid >> 6;
  const int wm = w >> 1, wn = w & 1;
  const int mblk = blockIdx.y, nblk = blockIdx.x;

  // per-lane global byte addrs of (frag = 2w, kt = 0); next frag is +16384 bytes
  const char* gAh = (const char*)Ah + (((size_t)(mblk * 8 + 2 * w) * 16) * 64 + l) * 16;
  const char* gAl = (const char*)Al + (((size_t)(mblk * 8 + 2 * w) * 16) * 64 + l) * 16;
  const char* gBh = (const char*)Bh + (((size_t)(nblk * 8 + 2 * w) * 16) * 64 + l) * 16;
  const char* gBl = (const char*)Bl + (((size_t)(nblk * 8 + 2 * w) * 16) * 64 + l) * 16;

  f32x4 acc[4][4];
#pragma unroll
  for (int i = 0; i < 4; ++i)
#pragma unroll
    for (int j = 0; j < 4; ++j) acc[i][j] = (f32x4){0.f, 0.f, 0.f, 0.f};

  auto stage = [&](int buf, int kt) {
    char* base = smem + buf * 32768;
    const size_t ko = (size_t)kt * 1024;
    char* dA0 = base + (2 * w) * 1024;            // wave-uniform LDS dests
    char* dA1 = base + 8192 + (2 * w) * 1024;
    char* dB0 = base + 16384 + (2 * w) * 1024;
    char* dB1 = base + 24576 + (2 * w) * 1024;
    gload16(gAh + ko,         dA0);
    gload16(gAh + ko + 16384, dA0 + 1024);
    gload16(gAl + ko,         dA1);
    gload16(gAl + ko + 16384, dA1 + 1024);
    gload16(gBh + ko,         dB0);
    gload16(gBh + ko + 16384, dB0 + 1024);
    gload16(gBl + ko,         dB1);
    gload16(gBl + ko + 16384, dB1 + 1024);
  };

  auto compute = [&](int buf) {
    const char* base = smem + buf * 32768;
    const short8* sAh = (const short8*)(base);
    const short8* sAl = (const short8*)(base + 8192);
    const short8* sBh = (const short8*)(base + 16384);
    const short8* sBl = (const short8*)(base + 24576);
    short8 a_h[4], a_l[4], b_h[4], b_l[4];
#pragma unroll
    for (int i = 0; i < 4; ++i) {
      a_h[i] = sAh[(wm * 4 + i) * 64 + l];
      a_l[i] = sAl[(wm * 4 + i) * 64 + l];
    }
#pragma unroll
    for (int j = 0; j < 4; ++j) {
      b_h[j] = sBh[(wn * 4 + j) * 64 + l];
      b_l[j] = sBl[(wn * 4 + j) * 64 + l];
    }
#pragma unroll
    for (int i = 0; i < 4; ++i)
#pragma unroll
      for (int j = 0; j < 4; ++j) {
        acc[i][j] = __builtin_amdgcn_mfma_f32_16x16x32_bf16(a_h[i], b_h[j], acc[i][j], 0, 0, 0);
        acc[i][j] = __builtin_amdgcn_mfma_f32_16x16x32_bf16(a_h[i], b_l[j], acc[i][j], 0, 0, 0);
        acc[i][j] = __builtin_amdgcn_mfma_f32_16x16x32_bf16(a_l[i], b_h[j], acc[i][j], 0, 0, 0);
      }
  };

  // T3-min 2-phase: prefetch tile t+1 while computing tile t; ONE barrier per step.
  stage(0, 0);
  __syncthreads();                 // vmcnt(0) drained by compiler before barrier
  int cur = 0;
#pragma unroll 1
  for (int kt = 1; kt < 16; ++kt) {
    stage(cur ^ 1, kt);            // issue next-tile loads (other buffer)
    compute(cur);                  // ds_read + 48 MFMA hide the load latency
    __syncthreads();               // drains stage; protects buf reuse next iter
    cur ^= 1;
  }
  compute(cur);

  // epilogue: D col = lane&15, row = (lane>>4)*4 + r  (m89/m91-verified layout)
  const int colb = nblk * 128 + wn * 64 + (l & 15);
  const int rowb = mblk * 128 + wm * 64 + ((l >> 4) << 2);
#pragma unroll
  for (int j = 0; j < 4; ++j) {
    float bv = bias[colb + j * 16];
#pragma unroll
    for (int i = 0; i < 4; ++i) {
#pragma unroll
      for (int r = 0; r < 4; ++r) {
        float v = acc[i][j][r] + bv;
        if (RELU) v = fmaxf(v, 0.f);
        C[(size_t)(rowb + i * 16 + r) * 512 + colb + j * 16] = v;
      }
    }
  }
}

// ---------- z = LN(h @ W2_in + b2) over C=8; one wave per token ----------
__global__ __launch_bounds__(256) void zln_kernel(const float* __restrict__ h,
    const float* __restrict__ W2, const float* __restrict__ b2,
    const float* __restrict__ g, const float* __restrict__ b,
    float* __restrict__ z) {
  int token = blockIdx.x * 4 + (threadIdx.x >> 6);
  int lane = threadIdx.x & 63;
  const float* hr = h + (size_t)token * E_DIM;
  float acc[C_DIM];
#pragma unroll
  for (int c = 0; c < C_DIM; ++c) acc[c] = 0.f;
  for (int e = lane; e < E_DIM; e += 64) {
    float hv = hr[e];
    const float* w = W2 + e * C_DIM;
#pragma unroll
    for (int c = 0; c < C_DIM; ++c) acc[c] = fmaf(hv, w[c], acc[c]);
  }
#pragma unroll
  for (int c = 0; c < C_DIM; ++c) {
#pragma unroll
    for (int off = 32; off > 0; off >>= 1) acc[c] += __shfl_down(acc[c], off);
  }
  if (lane == 0) {
    float v[C_DIM]; float mu = 0.f;
#pragma unroll
    for (int c = 0; c < C_DIM; ++c) { v[c] = acc[c] + b2[c]; mu += v[c]; }
    mu *= 0.125f;
    float var = 0.f;
#pragma unroll
    for (int c = 0; c < C_DIM; ++c) { float d = v[c] - mu; var += d * d; }
    var *= 0.125f;
    float inv = 1.0f / sqrtf(var + LN_EPS);
#pragma unroll
    for (int c = 0; c < C_DIM; ++c)
      z[(size_t)token * C_DIM + c] = ((v[c] - mu) * inv) * g[c] + b[c];
  }
}

// ---------- partial argmin: lane=token, code index uniform (scalar loads) ----------
__global__ __launch_bounds__(256) void vq_partial(const float* __restrict__ z,
    const float* __restrict__ emb, const float* __restrict__ ne,
    float* __restrict__ pbest, int* __restrict__ pidx) {
  int chunk = blockIdx.x & 7;                 // 8 chunks of 1024 codes
  int token = (blockIdx.x >> 3) * 256 + threadIdx.x;
  float zv[C_DIM];
#pragma unroll
  for (int c = 0; c < C_DIM; ++c) zv[c] = z[(size_t)token * C_DIM + c];
  float s = 0.f;
#pragma unroll
  for (int c = 0; c < C_DIM; ++c) s = fmaf(zv[c], zv[c], s);
  float best = 3.402823466e38f; int bi = 0;
  int j0 = chunk * 1024;
  for (int j = j0; j < j0 + 1024; ++j) {
    const float* e = emb + (size_t)j * C_DIM;  // uniform address -> s_load
    float p = 0.f;
#pragma unroll
    for (int c = 0; c < C_DIM; ++c) p = fmaf(zv[c], e[c], p);
    float d = fmaf(-2.f, p, s) + ne[j];
    if (d < best) { best = d; bi = j; }        // strict < : first-occurrence argmin
  }
  pbest[chunk * N_TOK + token] = best;
  pidx[chunk * N_TOK + token] = bi;
}

// ---------- combine 8 chunk-partials (ascending chunk keeps first-occurrence) ----------
__global__ void vq_combine(const float* __restrict__ pbest, const int* __restrict__ pidx,
    int* __restrict__ idx_i, float* __restrict__ idxf) {
  int n = blockIdx.x * 256 + threadIdx.x;
  float best = pbest[n]; int bi = pidx[n];
#pragma unroll
  for (int c = 1; c < 8; ++c) {
    float bb = pbest[c * N_TOK + n]; int i2 = pidx[c * N_TOK + n];
    if (bb < best) { best = bb; bi = i2; }
  }
  idx_i[n] = bi;
  idxf[n] = (float)bi;
}

// ---------- fused: relu(emb @ W1_out + b1_out) emitted directly in packed hi/lo layout ----------
// packed entry t = (mf*16 + kt)*64 + l holds code mf*16+(l&15), e-cols kt*32+(l>>4)*8 .. +7
__global__ __launch_bounds__(256) void proj_out1_pack(const float* __restrict__ emb,
    const float* __restrict__ W1, const float* __restrict__ b1,
    unsigned short* __restrict__ hi, unsigned short* __restrict__ lo) {
  int mf = blockIdx.x;                 // 0..511
  int l = threadIdx.x & 63;
  int kt4 = threadIdx.x >> 6;          // 0..3
  int k0 = mf * 16 + (l & 15);
  float ev[C_DIM];
#pragma unroll
  for (int c = 0; c < C_DIM; ++c) ev[c] = emb[(size_t)k0 * C_DIM + c];
#pragma unroll
  for (int it = 0; it < 4; ++it) {
    int kt = it * 4 + kt4;
    int e0 = kt * 32 + (l >> 4) * 8;
    float o[8];
    float4 bv0 = *(const float4*)(b1 + e0);
    float4 bv1 = *(const float4*)(b1 + e0 + 4);
    o[0] = bv0.x; o[1] = bv0.y; o[2] = bv0.z; o[3] = bv0.w;
    o[4] = bv1.x; o[5] = bv1.y; o[6] = bv1.z; o[7] = bv1.w;
#pragma unroll
    for (int c = 0; c < C_DIM; ++c) {
      float4 w0 = *(const float4*)(W1 + (size_t)c * E_DIM + e0);
      float4 w1 = *(const float4*)(W1 + (size_t)c * E_DIM + e0 + 4);
      o[0] = fmaf(ev[c], w0.x, o[0]); o[1] = fmaf(ev[c], w0.y, o[1]);
      o[2] = fmaf(ev[c], w0.z, o[2]); o[3] = fmaf(ev[c], w0.w, o[3]);
      o[4] = fmaf(ev[c], w1.x, o[4]); o[5] = fmaf(ev[c], w1.y, o[5]);
      o[6] = fmaf(ev[c], w1.z, o[6]); o[7] = fmaf(ev[c], w1.w, o[7]);
    }
    unsigned hw[4], lw[4];
#pragma unroll
    for (int p = 0; p < 4; ++p) {
      float a = fmaxf(o[2 * p], 0.f), b = fmaxf(o[2 * p + 1], 0.f);
      unsigned short ha = bf16_rn(a), hb = bf16_rn(b);
      unsigned short la = bf16_rn(a - bf16_f(ha)), lb = bf16_rn(b - bf16_f(hb));
      hw[p] = (unsigned)ha | ((unsigned)hb << 16);
      lw[p] = (unsigned)la | ((unsigned)lb << 16);
    }
    size_t t = ((size_t)mf * 16 + kt) * 64 + l;
    uint4 hv; hv.x = hw[0]; hv.y = hw[1]; hv.z = hw[2]; hv.w = hw[3];
    uint4 lv; lv.x = lw[0]; lv.y = lw[1]; lv.z = lw[2]; lv.w = lw[3];
    ((uint4*)hi)[t] = hv;
    ((uint4*)lo)[t] = lv;
  }
}

// ---------- in-place LayerNorm over rows of 512 ----------
__global__ __launch_bounds__(256) void ln512(float* __restrict__ g,
    const float* __restrict__ gw, const float* __restrict__ bw) {
  int row = blockIdx.x; int tid = threadIdx.x;
  float* r = g + (size_t)row * E_DIM;
  float v0 = r[tid], v1 = r[tid + 256];
  __shared__ float red[8];
  int lane = tid & 63, wid = tid >> 6;
  float sum = v0 + v1;
#pragma unroll
  for (int off = 32; off > 0; off >>= 1) sum += __shfl_xor(sum, off);
  if (lane == 0) red[wid] = sum;
  __syncthreads();
  float mu = (red[0] + red[1] + red[2] + red[3]) * (1.0f / 512.0f);
  float d0 = v0 - mu, d1 = v1 - mu;
  float sq = d0 * d0 + d1 * d1;
#pragma unroll
  for (int off = 32; off > 0; off >>= 1) sq += __shfl_xor(sq, off);
  if (lane == 0) red[4 + wid] = sq;
  __syncthreads();
  float var = (red[4] + red[5] + red[6] + red[7]) * (1.0f / 512.0f);
  float inv = 1.0f / sqrtf(var + LN_EPS);
  r[tid]       = (d0 * inv) * gw[tid] + bw[tid];
  r[tid + 256] = (d1 * inv) * gw[tid + 256] + bw[tid + 256];
}

// ---------- q[n] = oc[idx[n]] ----------
__global__ __launch_bounds__(128) void out_gather(const float* __restrict__ oc,
    const int* __restrict__ idx_i, float* __restrict__ q) {
  int n = blockIdx.x;
  int k = idx_i[n];
  int e = threadIdx.x * 4;
  *(float4*)(q + (size_t)n * E_DIM + e) = *(const float4*)(oc + (size_t)k * E_DIM + e);
}

// ---------- scatter ones into zeroed encodings ----------
__global__ void scatter_ones(const float* __restrict__ idxf, float* __restrict__ enc) {
  int n = blockIdx.x * 256 + threadIdx.x;
  int k = (int)idxf[n];
  enc[(size_t)n * K_CODES + k] = 1.0f;
}

extern "C" void kernel_launch(void* const* d_in, const int* in_sizes, int n_in,
                              void* d_out, int out_size, void* d_ws, size_t ws_size,
                              hipStream_t stream) {
  const float* features = (const float*)d_in[0];
  const float* W1_in  = (const float*)d_in[1];
  const float* b1_in  = (const float*)d_in[2];
  const float* W2_in  = (const float*)d_in[3];
  const float* b2_in  = (const float*)d_in[4];
  const float* ln_in_g = (const float*)d_in[5];
  const float* ln_in_b = (const float*)d_in[6];
  const float* emb    = (const float*)d_in[7];
  const float* W1_out = (const float*)d_in[8];
  const float* b1_out = (const float*)d_in[9];
  const float* W2_out = (const float*)d_in[10];
  const float* b2_out = (const float*)d_in[11];
  const float* ln_out_g = (const float*)d_in[12];
  const float* ln_out_b = (const float*)d_in[13];

  float* q    = (float*)d_out;                       // N*E
  float* idxf = q + (size_t)N_TOK * E_DIM;           // N (as float)
  float* enc  = idxf + N_TOK;                        // N*K one-hot

  // Use the 537 MB encodings region as scratch; memset+scatter happen last.
  float* h     = enc;                        // 16384*512
  float* g     = enc + 12582912;             // 8192*512
  float* z     = enc + 16777216;             // 16384*8
  float* ne    = enc + 16908288;             // 8192
  float* pbest = enc + 16916480;             // 8*16384
  int*   idx_i = (int*)(enc + 17047552);     // 16384
  int*   pidx  = (int*)(enc + 17063936);     // 8*16384
  unsigned short* A1h = (unsigned short*)(enc + 17195008);  // 16384*512 bf16
  unsigned short* A1l = (unsigned short*)(enc + 21389312);
  unsigned short* A2h = (unsigned short*)(enc + 25583616);  // 8192*512 bf16
  unsigned short* A2l = (unsigned short*)(enc + 27680768);
  unsigned short* B1h = (unsigned short*)(enc + 29777920);  // 512*512 bf16
  unsigned short* B1l = (unsigned short*)(enc + 29908992);
  unsigned short* B2h = (unsigned short*)(enc + 30040064);
  unsigned short* B2l = (unsigned short*)(enc + 30171136);

  // ---- fused prep: pack A1 (features), B1 (W1_in), B2 (W2_out), code norms ----
  prep<<<4384, 256, 0, stream>>>(features, W1_in, W2_out, emb,
                                 A1h, A1l, B1h, B1l, B2h, B2l, ne);

  // ---- project_in: h = relu(features @ W1_in + b1) via pipelined split-bf16 MFMA ----
  dim3 g1(4, N_TOK / 128);
  gemm_mfma<true><<<g1, 256, 0, stream>>>(A1h, A1l, B1h, B1l, b1_in, h);

  zln_kernel<<<N_TOK / 4, 256, 0, stream>>>(h, W2_in, b2_in, ln_in_g, ln_in_b, z);

  vq_partial<<<(N_TOK / 256) * 8, 256, 0, stream>>>(z, emb, ne, pbest, pidx);
  vq_combine<<<N_TOK / 256, 256, 0, stream>>>(pbest, pidx, idx_i, idxf);

  // ---- project_out over codebook: packed relu(emb@W1_out+b1) -> GEMM -> LN ----
  proj_out1_pack<<<K_CODES / 16, 256, 0, stream>>>(emb, W1_out, b1_out, A2h, A2l);
  dim3 g2(4, K_CODES / 128);
  gemm_mfma<false><<<g2, 256, 0, stream>>>(A2h, A2l, B2h, B2l, b2_out, g);

  ln512<<<K_CODES, 256, 0, stream>>>(g, ln_out_g, ln_out_b);

  out_gather<<<N_TOK, 128, 0, stream>>>(g, idx_i, q);

  hipMemsetAsync(enc, 0, (size_t)N_TOK * K_CODES * sizeof(float), stream);
  scatter_ones<<<N_TOK / 256, 256, 0, stream>>>(idxf, enc);
}